// Round 2
// baseline (493.223 us; speedup 1.0000x reference)
//
#include <hip/hip_runtime.h>
#include <hip/hip_bf16.h>

typedef __bf16 bf16;
typedef __bf16 bf16x8 __attribute__((ext_vector_type(8)));
typedef float f32x4 __attribute__((ext_vector_type(4)));

#define NU 20000
#define NO 10000
#define CDIM 256
#define TDIM 1536
#define EN 10000
#define VOCAB 101
#define MAXP 16
#define CAP 32

// output element offsets (FLOAT32 elements)
#define NODE_OFF 53760000LL
#define COL_OFF  53970000LL
#define TAB_OFF  54180000LL
#define F2P_OFF  54390000LL
#define NN_OFF   57750000LL

// ---- mega-grid partition: GEMM blocks FIRST so CUs grab long-running
// ---- MFMA work immediately; write-bound misc/idx blocks fill the
// ---- remaining occupancy slots and overlap with the GEMM.
#define GEMM_U_BLKS 314                        // 157 m-blocks x 2 n-blocks
#define GEMM_O_BLKS 158                        // 79 x 2
#define MISC_BLKS   22500
#define IDX_BLKS    840
#define MISC_OFF    (GEMM_U_BLKS + GEMM_O_BLKS)   // 472
#define IDX_OFF     (MISC_OFF + MISC_BLKS)        // 22972
#define TOTAL_BLKS  (IDX_OFF + IDX_BLKS)          // 23812

// ---- prep-grid partition: edges_fill + fp32->bf16 converts (A_u, A_o, W_u, W_o)
#define P_EDGE  40                              // ceil(EN/256)
#define P_CVU   (P_EDGE + 7500)                 // 20000*1536/4096
#define P_CVO   (P_CVU + 3750)                  // 10000*1536/4096
#define P_CVWU  (P_CVO + 96)                    // 256*1536/4096
#define P_CVWO  (P_CVWU + 96)
#define PREP_BLKS P_CVWO                        // 11482

// ---- workspace layout (bytes) ----
#define WS_PAIRS_OFF 65536ULL
#define WS_TBL_OFF   (WS_PAIRS_OFF + (unsigned long long)NO * CAP * 8)   // +2,560,000
#define WS_AB_U_OFF  (WS_TBL_OFF + (unsigned long long)NO * MAXP * 4)    // 3,265,536
#define WS_AB_O_OFF  (WS_AB_U_OFF + (unsigned long long)NU * TDIM * 2)   // +61,440,000
#define WS_WB_U_OFF  (WS_AB_O_OFF + (unsigned long long)NO * TDIM * 2)   // +30,720,000
#define WS_WB_O_OFF  (WS_WB_U_OFF + (unsigned long long)CDIM * TDIM * 2) // +786,432
#define WS_NEED      (WS_WB_O_OFF + (unsigned long long)CDIM * TDIM * 2)

// ================= edge table build =================
__device__ __forceinline__ void edges_body(int eblk, const int* __restrict__ edge,
                                           int* __restrict__ counts,
                                           unsigned long long* __restrict__ pairs)
{
    int e = eblk * 256 + threadIdx.x;
    if (e >= EN) return;
    int child = edge[e];                      // edge_index[0][e], in [0, NO)
    unsigned parent = (unsigned)edge[EN + e]; // edge_index[1][e]
    int slot = atomicAdd(&counts[child], 1);
    if (slot < CAP)
        pairs[child * CAP + slot] = ((unsigned long long)(unsigned)e << 32) | parent;
}

__global__ void build_tbl(const int* __restrict__ counts,
                          const unsigned long long* __restrict__ pairs,
                          int* __restrict__ tbl)
{
    int mm = blockIdx.x * 256 + threadIdx.x;
    if (mm >= NO) return;
    int cnt = counts[mm];
    if (cnt > CAP) cnt = CAP;
    unsigned long long v[CAP];
    for (int i = 0; i < cnt; i++) v[i] = pairs[mm * CAP + i];
    // insertion sort by packed (edge_id<<32 | parent) => stable by original edge order
    for (int i = 1; i < cnt; i++) {
        unsigned long long key = v[i];
        int j = i - 1;
        while (j >= 0 && v[j] > key) { v[j + 1] = v[j]; j--; }
        v[j + 1] = key;
    }
#pragma unroll
    for (int j = 0; j < MAXP; j++)
        tbl[mm * MAXP + j] = (j < cnt) ? (int)(v[j] & 0xffffffffULL) : -1;
}

// ================= fp32 -> bf16 convert (16 elems/thread) =================
__device__ __forceinline__ void conv_body(const float* __restrict__ src,
                                          bf16* __restrict__ dst, int relblk)
{
    long long e = (long long)relblk * 4096 + (long long)threadIdx.x * 16;
    float4 f0 = *(const float4*)&src[e];
    float4 f1 = *(const float4*)&src[e + 4];
    float4 f2 = *(const float4*)&src[e + 8];
    float4 f3 = *(const float4*)&src[e + 12];
    bf16x8 h0 = {(bf16)f0.x, (bf16)f0.y, (bf16)f0.z, (bf16)f0.w,
                 (bf16)f1.x, (bf16)f1.y, (bf16)f1.z, (bf16)f1.w};
    bf16x8 h1 = {(bf16)f2.x, (bf16)f2.y, (bf16)f2.z, (bf16)f2.w,
                 (bf16)f3.x, (bf16)f3.y, (bf16)f3.z, (bf16)f3.w};
    *(bf16x8*)&dst[e]     = h0;
    *(bf16x8*)&dst[e + 8] = h1;
}

__global__ __launch_bounds__(256) void prep(
    const int* __restrict__ edge, int* __restrict__ counts,
    unsigned long long* __restrict__ pairs,
    const float* __restrict__ users_text, const float* __restrict__ orders_text,
    const float* __restrict__ utw, const float* __restrict__ otw,
    bf16* __restrict__ AbU, bf16* __restrict__ AbO,
    bf16* __restrict__ WbU, bf16* __restrict__ WbO)
{
    int b = blockIdx.x;
    if (b < P_EDGE)       edges_body(b, edge, counts, pairs);
    else if (b < P_CVU)   conv_body(users_text,  AbU, b - P_EDGE);
    else if (b < P_CVO)   conv_body(orders_text, AbO, b - P_CVU);
    else if (b < P_CVWU)  conv_body(utw, WbU, b - P_CVO);
    else                  conv_body(otw, WbO, b - P_CVWU);
}

// ================= indices + f2p + num_nodes (float32 out) =================
__device__ __forceinline__ void idx_body(int iblk, const int* __restrict__ tbl,
                                         float* __restrict__ out)
{
    int i = iblk * 256 + threadIdx.x;
    if (i >= 210000) return;
    float nodev, colvf, tabv;
    int m = -1;
    if (i < 140000) {
        int n = i % 20000;
        nodev = (float)n; colvf = (float)(i / 20000); tabv = 0.f;
    } else {
        int i2 = i - 140000;
        m = i2 % 10000;
        nodev = (float)(20000 + m); colvf = (float)(7 + i2 / 10000); tabv = 1.f;
    }
    out[NODE_OFF + i] = nodev;
    out[COL_OFF + i]  = colvf;
    out[TAB_OFF + i]  = tabv;

    float h[16];
    if (m < 0) {
#pragma unroll
        for (int j = 0; j < 16; j++) h[j] = -1.f;
    } else {
#pragma unroll
        for (int j = 0; j < 16; j++) h[j] = (float)tbl[m * MAXP + j];
    }
    float4* dst = (float4*)&out[F2P_OFF + (long long)i * 16];
#pragma unroll
    for (int j = 0; j < 4; j++)
        dst[j] = *(const float4*)&h[j * 4];
    if (i == 0) out[NN_OFF] = 30000.f;
}

// ================= num + cat tokens (k = 0..5 of each table) =================
__device__ __forceinline__ void misc_body(int mb,
    const float* __restrict__ unum, const int* __restrict__ ucat,
    const float* __restrict__ onum, const int* __restrict__ ocat,
    const float* __restrict__ temb,
    const float* __restrict__ unw, const float* __restrict__ unb,
    const float* __restrict__ uctab, const float* __restrict__ ucol,
    const float* __restrict__ onw, const float* __restrict__ onb,
    const float* __restrict__ octab, const float* __restrict__ ocol,
    float* __restrict__ out)
{
    int t = threadIdx.x;
    int ridx = mb * 8 + (t >> 5);            // 0..179999 (exact)
    int c0 = (t & 31) * 8;
    bool isU = ridx < 120000;
    int k, n; long long orow;
    const float *num, *nw, *nb, *ctab, *colw, *te;
    const int* cat;
    if (isU) {
        k = ridx / 20000; n = ridx - k * 20000; orow = ridx;
        num = unum; cat = ucat; nw = unw; nb = unb; ctab = uctab; colw = ucol; te = temb;
    } else {
        int i2 = ridx - 120000;
        k = i2 / 10000; n = i2 - k * 10000; orow = (long long)ridx + 20000;
        num = onum; cat = ocat; nw = onw; nb = onb; ctab = octab; colw = ocol; te = temb + CDIM;
    }
    float colv[8], tev[8];
    *(float4*)&colv[0] = *(const float4*)&colw[k * CDIM + c0];
    *(float4*)&colv[4] = *(const float4*)&colw[k * CDIM + c0 + 4];
    *(float4*)&tev[0]  = *(const float4*)&te[c0];
    *(float4*)&tev[4]  = *(const float4*)&te[c0 + 4];
    float res[8];
    if (k < 3) {
        float v = num[n * 3 + k];
        float wv[8], bv[8];
        *(float4*)&wv[0] = *(const float4*)&nw[k * CDIM + c0];
        *(float4*)&wv[4] = *(const float4*)&nw[k * CDIM + c0 + 4];
        *(float4*)&bv[0] = *(const float4*)&nb[k * CDIM + c0];
        *(float4*)&bv[4] = *(const float4*)&nb[k * CDIM + c0 + 4];
#pragma unroll
        for (int j = 0; j < 8; j++) {
            float x = v * wv[j] + bv[j];
            float s = x / (1.f + __expf(-x));   // silu
            res[j] = s + colv[j] + tev[j];
        }
    } else {
        int cv = cat[n * 3 + (k - 3)];
        float tcv[8];
        *(float4*)&tcv[0] = *(const float4*)&ctab[((k - 3) * VOCAB + cv) * CDIM + c0];
        *(float4*)&tcv[4] = *(const float4*)&ctab[((k - 3) * VOCAB + cv) * CDIM + c0 + 4];
#pragma unroll
        for (int j = 0; j < 8; j++)
            res[j] = tcv[j] + colv[j] + tev[j];
    }
    *(float4*)&out[orow * CDIM + c0]     = *(const float4*)&res[0];
    *(float4*)&out[orow * CDIM + c0 + 4] = *(const float4*)&res[4];
}

// ================= bf16 GEMM (m97 structure): D = A(MxK)*W(NxK)^T + bias =================
// A, W pre-converted bf16; staged straight into linear [128][64] LDS tiles via
// 16B global_load_lds (no VGPR round-trip, no VALU converts in the staging path).
__device__ __forceinline__ void gload16(const void* g, void* l)
{
    __builtin_amdgcn_global_load_lds(
        (const __attribute__((address_space(1))) void*)g,
        (__attribute__((address_space(3))) void*)l, 16, 0, 0);
}

__device__ __forceinline__ void gemm_bf16_body(
    const bf16* __restrict__ A, const bf16* __restrict__ W,
    const float* __restrict__ tbias, const float* __restrict__ colw,
    const float* __restrict__ temb, float* __restrict__ out,
    int M, long long out_row_base, int mblk, int nblk,
    bf16* As, bf16* Bs)
{
    const int tid = threadIdx.x;
    const int m0 = mblk * 128;
    const int n0 = nblk * 128;
    const int w = tid >> 6, lane = tid & 63;
    const int wm = (w & 1) * 64, wn = (w >> 1) * 64;
    const int lrow = lane & 15, lquad = lane >> 4;

    // per-lane staging coords: chunk ch covers LDS bytes [ch*16, ch*16+16)
    // row = ch>>3 (64 bf16 = 128B per row), col8 = (ch&7)*8
    f32x4 acc[4][4];
#pragma unroll
    for (int a = 0; a < 4; a++)
#pragma unroll
        for (int b = 0; b < 4; b++) acc[a][b] = (f32x4){0.f, 0.f, 0.f, 0.f};

    for (int k0 = 0; k0 < TDIM; k0 += 64) {
        __syncthreads();
#pragma unroll
        for (int i = 0; i < 4; i++) {
            int ch = i * 256 + w * 64 + lane;     // 0..1023
            int row = ch >> 3, col8 = (ch & 7) * 8;
            int ga = m0 + row; if (ga >= M) ga = M - 1;   // clamp; stores predicated
            gload16(&A[(size_t)ga * TDIM + k0 + col8], &As[(size_t)(i * 256 + w * 64) * 8]);
            gload16(&W[(size_t)(n0 + row) * TDIM + k0 + col8], &Bs[(size_t)(i * 256 + w * 64) * 8]);
        }
        __syncthreads();   // compiler emits vmcnt(0) drain before barrier
#pragma unroll
        for (int ks = 0; ks < 2; ks++) {
            bf16x8 afr[4], bfr[4];
#pragma unroll
            for (int mi = 0; mi < 4; mi++)
                afr[mi] = *(const bf16x8*)&As[(wm + mi * 16 + lrow) * 64 + ks * 32 + lquad * 8];
#pragma unroll
            for (int ni = 0; ni < 4; ni++)
                bfr[ni] = *(const bf16x8*)&Bs[(wn + ni * 16 + lrow) * 64 + ks * 32 + lquad * 8];
#pragma unroll
            for (int mi = 0; mi < 4; mi++)
#pragma unroll
                for (int ni = 0; ni < 4; ni++)
                    acc[mi][ni] = __builtin_amdgcn_mfma_f32_16x16x32_bf16(
                        afr[mi], bfr[ni], acc[mi][ni], 0, 0, 0);
        }
    }

    // epilogue: + txt_b[c] + col[6][c] + table_emb[c], write fp32
#pragma unroll
    for (int ni = 0; ni < 4; ni++) {
        int c = n0 + wn + ni * 16 + lrow;
        float bias = tbias[c] + colw[6 * CDIM + c] + temb[c];
#pragma unroll
        for (int mi = 0; mi < 4; mi++) {
            int mbase = m0 + wm + mi * 16 + lquad * 4;
#pragma unroll
            for (int r = 0; r < 4; r++) {
                int m = mbase + r;
                if (m < M)
                    out[(out_row_base + m) * CDIM + c] = acc[mi][ni][r] + bias;
            }
        }
    }
}

// ================= fp32 reg-staged GEMM (fallback path only) =================
__device__ __forceinline__ void gemm_f32_body(
    const float* __restrict__ A, const float* __restrict__ W,
    const float* __restrict__ tbias, const float* __restrict__ colw,
    const float* __restrict__ temb, float* __restrict__ out,
    int M, long long out_row_base, int mblk, int nblk,
    bf16* As, bf16* Bs)
{
    constexpr int LDA = 72; // bf16 elems; +8 pad
    const int tid = threadIdx.x;
    const int m0 = mblk * 128;
    const int n0 = nblk * 128;
    const int w = tid >> 6, lane = tid & 63;
    const int wm = (w & 1) * 64, wn = (w >> 1) * 64;
    const int lrow = lane & 15, lquad = lane >> 4;

    f32x4 acc[4][4];
#pragma unroll
    for (int a = 0; a < 4; a++)
#pragma unroll
        for (int b = 0; b < 4; b++) acc[a][b] = (f32x4){0.f, 0.f, 0.f, 0.f};

    for (int k0 = 0; k0 < TDIM; k0 += 64) {
        __syncthreads();
#pragma unroll
        for (int i = 0; i < 8; i++) {
            int c = tid + i * 256;
            int row = c >> 4;
            int col4 = (c & 15) << 2;
            int ga = m0 + row; if (ga >= M) ga = M - 1;
            float4 av = *(const float4*)&A[(size_t)ga * TDIM + k0 + col4];
            __attribute__((aligned(8))) bf16 ha[4] =
                {(bf16)av.x, (bf16)av.y, (bf16)av.z, (bf16)av.w};
            *(unsigned long long*)&As[row * LDA + col4] = *(const unsigned long long*)ha;
            float4 bv = *(const float4*)&W[(size_t)(n0 + row) * TDIM + k0 + col4];
            __attribute__((aligned(8))) bf16 hb[4] =
                {(bf16)bv.x, (bf16)bv.y, (bf16)bv.z, (bf16)bv.w};
            *(unsigned long long*)&Bs[row * LDA + col4] = *(const unsigned long long*)hb;
        }
        __syncthreads();
#pragma unroll
        for (int ks = 0; ks < 2; ks++) {
            bf16x8 afr[4], bfr[4];
#pragma unroll
            for (int mi = 0; mi < 4; mi++)
                afr[mi] = *(const bf16x8*)&As[(wm + mi * 16 + lrow) * LDA + ks * 32 + lquad * 8];
#pragma unroll
            for (int ni = 0; ni < 4; ni++)
                bfr[ni] = *(const bf16x8*)&Bs[(wn + ni * 16 + lrow) * LDA + ks * 32 + lquad * 8];
#pragma unroll
            for (int mi = 0; mi < 4; mi++)
#pragma unroll
                for (int ni = 0; ni < 4; ni++)
                    acc[mi][ni] = __builtin_amdgcn_mfma_f32_16x16x32_bf16(
                        afr[mi], bfr[ni], acc[mi][ni], 0, 0, 0);
        }
    }

#pragma unroll
    for (int ni = 0; ni < 4; ni++) {
        int c = n0 + wn + ni * 16 + lrow;
        float bias = tbias[c] + colw[6 * CDIM + c] + temb[c];
#pragma unroll
        for (int mi = 0; mi < 4; mi++) {
            int mbase = m0 + wm + mi * 16 + lquad * 4;
#pragma unroll
            for (int r = 0; r < 4; r++) {
                int m = mbase + r;
                if (m < M)
                    out[(out_row_base + m) * CDIM + c] = acc[mi][ni][r] + bias;
            }
        }
    }
}

// ================= fused mega-kernel (bf16-GEMM path) =================
__global__ __launch_bounds__(256) void mega(
    const float* __restrict__ users_num, const int* __restrict__ users_cat,
    const float* __restrict__ orders_num, const int* __restrict__ orders_cat,
    const float* __restrict__ temb,
    const float* __restrict__ unw, const float* __restrict__ unb,
    const float* __restrict__ uctab,
    const float* __restrict__ utb, const float* __restrict__ ucol,
    const float* __restrict__ onw, const float* __restrict__ onb,
    const float* __restrict__ octab,
    const float* __restrict__ otb, const float* __restrict__ ocol,
    const bf16* __restrict__ AbU, const bf16* __restrict__ AbO,
    const bf16* __restrict__ WbU, const bf16* __restrict__ WbO,
    const int* __restrict__ tbl, float* __restrict__ out)
{
    __shared__ bf16 As[128 * 64];
    __shared__ bf16 Bs[128 * 64];
    int b = blockIdx.x;
    if (b < GEMM_U_BLKS) {
        gemm_bf16_body(AbU, WbU, utb, ucol, temb, out,
                       NU, 120000LL, b >> 1, b & 1, As, Bs);
    } else if (b < MISC_OFF) {
        int bb = b - GEMM_U_BLKS;
        gemm_bf16_body(AbO, WbO, otb, ocol, temb + CDIM, out,
                       NO, 200000LL, bb >> 1, bb & 1, As, Bs);
    } else if (b < IDX_OFF) {
        misc_body(b - MISC_OFF, users_num, users_cat, orders_num, orders_cat,
                  temb, unw, unb, uctab, ucol, onw, onb, octab, ocol, out);
    } else {
        idx_body(b - IDX_OFF, tbl, out);
    }
}

// ================= fused mega-kernel (fallback: fp32 reg-staged GEMM) =================
__global__ __launch_bounds__(256) void mega_fb(
    const float* __restrict__ users_num, const int* __restrict__ users_cat,
    const float* __restrict__ users_text,
    const float* __restrict__ orders_num, const int* __restrict__ orders_cat,
    const float* __restrict__ orders_text,
    const float* __restrict__ temb,
    const float* __restrict__ unw, const float* __restrict__ unb,
    const float* __restrict__ uctab, const float* __restrict__ utw,
    const float* __restrict__ utb, const float* __restrict__ ucol,
    const float* __restrict__ onw, const float* __restrict__ onb,
    const float* __restrict__ octab, const float* __restrict__ otw,
    const float* __restrict__ otb, const float* __restrict__ ocol,
    const int* __restrict__ tbl, float* __restrict__ out)
{
    __shared__ bf16 As[128 * 72];
    __shared__ bf16 Bs[128 * 72];
    int b = blockIdx.x;
    if (b < GEMM_U_BLKS) {
        gemm_f32_body(users_text, utw, utb, ucol, temb, out,
                      NU, 120000LL, b >> 1, b & 1, As, Bs);
    } else if (b < MISC_OFF) {
        int bb = b - GEMM_U_BLKS;
        gemm_f32_body(orders_text, otw, otb, ocol, temb + CDIM, out,
                      NO, 200000LL, bb >> 1, bb & 1, As, Bs);
    } else if (b < IDX_OFF) {
        misc_body(b - MISC_OFF, users_num, users_cat, orders_num, orders_cat,
                  temb, unw, unb, uctab, ucol, onw, onb, octab, ocol, out);
    } else {
        idx_body(b - IDX_OFF, tbl, out);
    }
}

__global__ void edges_fill(const int* __restrict__ edge, int* __restrict__ counts,
                           unsigned long long* __restrict__ pairs)
{
    edges_body(blockIdx.x, edge, counts, pairs);
}

extern "C" void kernel_launch(void* const* d_in, const int* in_sizes, int n_in,
                              void* d_out, int out_size, void* d_ws, size_t ws_size,
                              hipStream_t stream)
{
    const float* users_num   = (const float*)d_in[0];
    const int*   users_cat   = (const int*)d_in[1];
    const float* users_text  = (const float*)d_in[2];
    const float* orders_num  = (const float*)d_in[3];
    const int*   orders_cat  = (const int*)d_in[4];
    const float* orders_text = (const float*)d_in[5];
    const int*   edge_index  = (const int*)d_in[6];
    const float* table_emb   = (const float*)d_in[7];
    const float* u_num_w   = (const float*)d_in[8];
    const float* u_num_b   = (const float*)d_in[9];
    const float* u_cat_tab = (const float*)d_in[10];
    const float* u_txt_w   = (const float*)d_in[11];
    const float* u_txt_b   = (const float*)d_in[12];
    const float* u_col     = (const float*)d_in[13];
    const float* o_num_w   = (const float*)d_in[14];
    const float* o_num_b   = (const float*)d_in[15];
    const float* o_cat_tab = (const float*)d_in[16];
    const float* o_txt_w   = (const float*)d_in[17];
    const float* o_txt_b   = (const float*)d_in[18];
    const float* o_col     = (const float*)d_in[19];
    float* out = (float*)d_out;

    int* counts = (int*)d_ws;
    unsigned long long* pairs = (unsigned long long*)((char*)d_ws + WS_PAIRS_OFF);
    int* tbl = (int*)((char*)d_ws + WS_TBL_OFF);

    hipMemsetAsync(counts, 0, NO * sizeof(int), stream);

    if (ws_size >= WS_NEED) {
        bf16* AbU = (bf16*)((char*)d_ws + WS_AB_U_OFF);
        bf16* AbO = (bf16*)((char*)d_ws + WS_AB_O_OFF);
        bf16* WbU = (bf16*)((char*)d_ws + WS_WB_U_OFF);
        bf16* WbO = (bf16*)((char*)d_ws + WS_WB_O_OFF);
        // prep: edges_fill + stream-convert A/W to bf16 (fused, one dispatch)
        prep<<<PREP_BLKS, 256, 0, stream>>>(edge_index, counts, pairs,
            users_text, orders_text, u_txt_w, o_txt_w, AbU, AbO, WbU, WbO);
        build_tbl<<<(NO + 255) / 256, 256, 0, stream>>>(counts, pairs, tbl);
        mega<<<TOTAL_BLKS, 256, 0, stream>>>(
            users_num, users_cat, orders_num, orders_cat,
            table_emb, u_num_w, u_num_b, u_cat_tab, u_txt_b, u_col,
            o_num_w, o_num_b, o_cat_tab, o_txt_b, o_col,
            AbU, AbO, WbU, WbO, tbl, out);
    } else {
        // fallback: workspace too small for bf16 copies
        edges_fill<<<P_EDGE, 256, 0, stream>>>(edge_index, counts, pairs);
        build_tbl<<<(NO + 255) / 256, 256, 0, stream>>>(counts, pairs, tbl);
        mega_fb<<<TOTAL_BLKS, 256, 0, stream>>>(
            users_num, users_cat, users_text, orders_num, orders_cat, orders_text,
            table_emb, u_num_w, u_num_b, u_cat_tab, u_txt_w, u_txt_b, u_col,
            o_num_w, o_num_b, o_cat_tab, o_txt_w, o_txt_b, o_col, tbl, out);
    }
}

// Round 3
// 457.296 us; speedup vs baseline: 1.0786x; 1.0786x over previous
//
#include <hip/hip_runtime.h>
#include <hip/hip_bf16.h>

typedef __bf16 bf16;
typedef __bf16 bf16x8 __attribute__((ext_vector_type(8)));
typedef float f32x4 __attribute__((ext_vector_type(4)));

#define NU 20000
#define NO 10000
#define CDIM 256
#define TDIM 1536
#define EN 10000
#define VOCAB 101
#define MAXP 16
#define CAP 32

// output element offsets (FLOAT32 elements)
#define NODE_OFF 53760000LL
#define COL_OFF  53970000LL
#define TAB_OFF  54180000LL
#define F2P_OFF  54390000LL
#define NN_OFF   57750000LL

// ---- mega-grid partition: GEMM blocks FIRST (long-running MFMA work),
// ---- coarse misc/idx blocks stream through remaining occupancy slots.
#define GEMM_U_BLKS 314                        // 157 m-blocks x 2 n-blocks
#define GEMM_O_BLKS 158                        // 79 x 2
#define MISC_BLKS   5625                       // 32 rows per block
#define IDX_BLKS    206                        // 1024 items per block
#define MISC_OFF    (GEMM_U_BLKS + GEMM_O_BLKS)   // 472
#define IDX_OFF     (MISC_OFF + MISC_BLKS)        // 6097
#define TOTAL_BLKS  (IDX_OFF + IDX_BLKS)          // 6303

// ---- prep-grid partition: edges_fill + W fp32->bf16 swizzled converts
#define P_EDGE  40                              // ceil(EN/256)
#define P_CVWU  (P_EDGE + 96)                   // 256*1536/4096
#define P_CVWO  (P_CVWU + 96)
#define PREP_BLKS P_CVWO                        // 232

// ---- workspace layout (bytes) ----
#define WS_PAIRS_OFF 65536ULL
#define WS_TBL_OFF   (WS_PAIRS_OFF + (unsigned long long)NO * CAP * 8)   // +2,560,000
#define WS_WB_U_OFF  (WS_TBL_OFF + (unsigned long long)NO * MAXP * 4)    // 3,265,536
#define WS_WB_O_OFF  (WS_WB_U_OFF + (unsigned long long)CDIM * TDIM * 2) // +786,432
#define WS_NEED      (WS_WB_O_OFF + (unsigned long long)CDIM * TDIM * 2) // ~4.84 MB

// ================= edge table build =================
__device__ __forceinline__ void edges_body(int eblk, const int* __restrict__ edge,
                                           int* __restrict__ counts,
                                           unsigned long long* __restrict__ pairs)
{
    int e = eblk * 256 + threadIdx.x;
    if (e >= EN) return;
    int child = edge[e];                      // edge_index[0][e], in [0, NO)
    unsigned parent = (unsigned)edge[EN + e]; // edge_index[1][e]
    int slot = atomicAdd(&counts[child], 1);
    if (slot < CAP)
        pairs[child * CAP + slot] = ((unsigned long long)(unsigned)e << 32) | parent;
}

__global__ void build_tbl(const int* __restrict__ counts,
                          const unsigned long long* __restrict__ pairs,
                          int* __restrict__ tbl)
{
    int mm = blockIdx.x * 256 + threadIdx.x;
    if (mm >= NO) return;
    int cnt = counts[mm];
    if (cnt > CAP) cnt = CAP;
    unsigned long long v[CAP];
    for (int i = 0; i < cnt; i++) v[i] = pairs[mm * CAP + i];
    // insertion sort by packed (edge_id<<32 | parent) => stable by original edge order
    for (int i = 1; i < cnt; i++) {
        unsigned long long key = v[i];
        int j = i - 1;
        while (j >= 0 && v[j] > key) { v[j + 1] = v[j]; j--; }
        v[j + 1] = key;
    }
#pragma unroll
    for (int j = 0; j < MAXP; j++)
        tbl[mm * MAXP + j] = (j < cnt) ? (int)(v[j] & 0xffffffffULL) : -1;
}

// ================= W fp32 -> bf16 convert, PRE-SWIZZLED =================
// Within each row's 64-elem k-block, 16B chunk c holds original chunk
// (c ^ (row&7)).  global_load_lds then stages LINEARLY; the GEMM's
// B-fragment ds_read applies the same XOR -> bank-uniform (T2 / rule 21:
// inverse-swz source + swz read, linear LDS dest).
__device__ __forceinline__ void conv_w_body(const float* __restrict__ src,
                                            bf16* __restrict__ dst, int relblk)
{
    int t = threadIdx.x;
    long long e = (long long)relblk * 4096 + (long long)t * 16;
    int row = (int)(e / TDIM);
    int col = (int)(e - (long long)row * TDIM);
    int kb = col >> 6;              // 64-elem k-block
    int cc = (col & 63) >> 3;       // chunk pair: cc, cc+1 (cc even)
    int x = row & 7;
    float4 f0 = *(const float4*)&src[e];
    float4 f1 = *(const float4*)&src[e + 4];
    float4 f2 = *(const float4*)&src[e + 8];
    float4 f3 = *(const float4*)&src[e + 12];
    bf16x8 h0 = {(bf16)f0.x, (bf16)f0.y, (bf16)f0.z, (bf16)f0.w,
                 (bf16)f1.x, (bf16)f1.y, (bf16)f1.z, (bf16)f1.w};
    bf16x8 h1 = {(bf16)f2.x, (bf16)f2.y, (bf16)f2.z, (bf16)f2.w,
                 (bf16)f3.x, (bf16)f3.y, (bf16)f3.z, (bf16)f3.w};
    long long base = (long long)row * TDIM + kb * 64;
    *(bf16x8*)&dst[base + ((cc ^ x) * 8)]       = h0;
    *(bf16x8*)&dst[base + (((cc + 1) ^ x) * 8)] = h1;
}

__global__ __launch_bounds__(256) void prep(
    const int* __restrict__ edge, int* __restrict__ counts,
    unsigned long long* __restrict__ pairs,
    const float* __restrict__ utw, const float* __restrict__ otw,
    bf16* __restrict__ WbU, bf16* __restrict__ WbO)
{
    int b = blockIdx.x;
    if (b < P_EDGE)       edges_body(b, edge, counts, pairs);
    else if (b < P_CVWU)  conv_w_body(utw, WbU, b - P_EDGE);
    else                  conv_w_body(otw, WbO, b - P_CVWU);
}

// ================= indices + f2p + num_nodes (float32 out) =================
__device__ __forceinline__ void idx_body(int iblk, const int* __restrict__ tbl,
                                         float* __restrict__ out)
{
#pragma unroll
    for (int it = 0; it < 4; it++) {
        int i = iblk * 1024 + it * 256 + threadIdx.x;
        if (i >= 210000) return;
        float nodev, colvf, tabv;
        int m = -1;
        if (i < 140000) {
            int n = i % 20000;
            nodev = (float)n; colvf = (float)(i / 20000); tabv = 0.f;
        } else {
            int i2 = i - 140000;
            m = i2 % 10000;
            nodev = (float)(20000 + m); colvf = (float)(7 + i2 / 10000); tabv = 1.f;
        }
        out[NODE_OFF + i] = nodev;
        out[COL_OFF + i]  = colvf;
        out[TAB_OFF + i]  = tabv;

        float h[16];
        if (m < 0) {
#pragma unroll
            for (int j = 0; j < 16; j++) h[j] = -1.f;
        } else {
#pragma unroll
            for (int j = 0; j < 16; j++) h[j] = (float)tbl[m * MAXP + j];
        }
        float4* dst = (float4*)&out[F2P_OFF + (long long)i * 16];
#pragma unroll
        for (int j = 0; j < 4; j++)
            dst[j] = *(const float4*)&h[j * 4];
        if (i == 0) out[NN_OFF] = 30000.f;
    }
}

// ================= num + cat tokens, 32 rows per block =================
__device__ __forceinline__ void misc_body(int mb,
    const float* __restrict__ unum, const int* __restrict__ ucat,
    const float* __restrict__ onum, const int* __restrict__ ocat,
    const float* __restrict__ temb,
    const float* __restrict__ unw, const float* __restrict__ unb,
    const float* __restrict__ uctab, const float* __restrict__ ucol,
    const float* __restrict__ onw, const float* __restrict__ onb,
    const float* __restrict__ octab, const float* __restrict__ ocol,
    float* __restrict__ out)
{
    int t = threadIdx.x;
    int c0 = (t & 31) * 8;
#pragma unroll
    for (int it = 0; it < 4; it++) {
        int ridx = mb * 32 + it * 8 + (t >> 5);   // 0..179999 (5625*32 exact)
        bool isU = ridx < 120000;
        int k, n; long long orow;
        const float *num, *nw, *nb, *ctab, *colw, *te;
        const int* cat;
        if (isU) {
            k = ridx / 20000; n = ridx - k * 20000; orow = ridx;
            num = unum; cat = ucat; nw = unw; nb = unb; ctab = uctab; colw = ucol; te = temb;
        } else {
            int i2 = ridx - 120000;
            k = i2 / 10000; n = i2 - k * 10000; orow = (long long)ridx + 20000;
            num = onum; cat = ocat; nw = onw; nb = onb; ctab = octab; colw = ocol; te = temb + CDIM;
        }
        float colv[8], tev[8];
        *(float4*)&colv[0] = *(const float4*)&colw[k * CDIM + c0];
        *(float4*)&colv[4] = *(const float4*)&colw[k * CDIM + c0 + 4];
        *(float4*)&tev[0]  = *(const float4*)&te[c0];
        *(float4*)&tev[4]  = *(const float4*)&te[c0 + 4];
        float res[8];
        if (k < 3) {
            float v = num[n * 3 + k];
            float wv[8], bv[8];
            *(float4*)&wv[0] = *(const float4*)&nw[k * CDIM + c0];
            *(float4*)&wv[4] = *(const float4*)&nw[k * CDIM + c0 + 4];
            *(float4*)&bv[0] = *(const float4*)&nb[k * CDIM + c0];
            *(float4*)&bv[4] = *(const float4*)&nb[k * CDIM + c0 + 4];
#pragma unroll
            for (int j = 0; j < 8; j++) {
                float x = v * wv[j] + bv[j];
                float s = x / (1.f + __expf(-x));   // silu
                res[j] = s + colv[j] + tev[j];
            }
        } else {
            int cv = cat[n * 3 + (k - 3)];
            float tcv[8];
            *(float4*)&tcv[0] = *(const float4*)&ctab[((k - 3) * VOCAB + cv) * CDIM + c0];
            *(float4*)&tcv[4] = *(const float4*)&ctab[((k - 3) * VOCAB + cv) * CDIM + c0 + 4];
#pragma unroll
            for (int j = 0; j < 8; j++)
                res[j] = tcv[j] + colv[j] + tev[j];
        }
        *(float4*)&out[orow * CDIM + c0]     = *(const float4*)&res[0];
        *(float4*)&out[orow * CDIM + c0 + 4] = *(const float4*)&res[4];
    }
}

// ================= hybrid GEMM: A fp32 reg-staged, W bf16 via global_load_lds =================
__device__ __forceinline__ void gload16(const void* g, void* l)
{
    __builtin_amdgcn_global_load_lds(
        (const __attribute__((address_space(1))) void*)g,
        (__attribute__((address_space(3))) void*)l, 16, 0, 0);
}

__device__ __forceinline__ void gemm_hyb_body(
    const float* __restrict__ A, const bf16* __restrict__ Wswz,
    const float* __restrict__ tbias, const float* __restrict__ colw,
    const float* __restrict__ temb, float* __restrict__ out,
    int M, long long out_row_base, int mblk, int nblk,
    bf16* As /*[128][72]*/, bf16* Bs /*[128][64] linear, swizzled content*/)
{
    const int tid = threadIdx.x;
    const int m0 = mblk * 128;
    const int n0 = nblk * 128;
    const int w = tid >> 6, lane = tid & 63;
    const int wm = (w & 1) * 64, wn = (w >> 1) * 64;
    const int lrow = lane & 15, lquad = lane >> 4;
    const int bxor = lrow & 7;     // B-read XOR (== row&7 since wn,ni*16 are mult of 8)

    f32x4 acc[4][4];
#pragma unroll
    for (int a = 0; a < 4; a++)
#pragma unroll
        for (int b = 0; b < 4; b++) acc[a][b] = (f32x4){0.f, 0.f, 0.f, 0.f};

    for (int k0 = 0; k0 < TDIM; k0 += 64) {
        __syncthreads();
        // B tile: 1024 16B-chunks straight into linear LDS (content pre-swizzled)
#pragma unroll
        for (int i = 0; i < 4; i++) {
            int ch = i * 256 + w * 64 + lane;     // 0..1023
            int row = ch >> 3, c8 = (ch & 7) * 8;
            gload16(&Wswz[(size_t)(n0 + row) * TDIM + k0 + c8],
                    &Bs[(size_t)(i * 256 + w * 64) * 8]);
        }
        // A tile: fp32 load + cvt + padded LDS store
#pragma unroll
        for (int i = 0; i < 8; i++) {
            int c = tid + i * 256;                // 0..2047 (4-float chunks)
            int row = c >> 4, col4 = (c & 15) << 2;
            int ga = m0 + row; if (ga >= M) ga = M - 1;   // clamp; stores predicated
            float4 av = *(const float4*)&A[(size_t)ga * TDIM + k0 + col4];
            __attribute__((aligned(8))) bf16 ha[4] =
                {(bf16)av.x, (bf16)av.y, (bf16)av.z, (bf16)av.w};
            *(unsigned long long*)&As[row * 72 + col4] = *(const unsigned long long*)ha;
        }
        __syncthreads();
#pragma unroll
        for (int ks = 0; ks < 2; ks++) {
            bf16x8 afr[4], bfr[4];
#pragma unroll
            for (int mi = 0; mi < 4; mi++)
                afr[mi] = *(const bf16x8*)&As[(wm + mi * 16 + lrow) * 72 + ks * 32 + lquad * 8];
#pragma unroll
            for (int ni = 0; ni < 4; ni++)
                bfr[ni] = *(const bf16x8*)&Bs[(wn + ni * 16 + lrow) * 64 +
                                              (((ks * 4 + lquad) ^ bxor) * 8)];
#pragma unroll
            for (int mi = 0; mi < 4; mi++)
#pragma unroll
                for (int ni = 0; ni < 4; ni++)
                    acc[mi][ni] = __builtin_amdgcn_mfma_f32_16x16x32_bf16(
                        afr[mi], bfr[ni], acc[mi][ni], 0, 0, 0);
        }
    }

    // epilogue: + txt_b[c] + col[6][c] + table_emb[c], write fp32
#pragma unroll
    for (int ni = 0; ni < 4; ni++) {
        int c = n0 + wn + ni * 16 + lrow;
        float bias = tbias[c] + colw[6 * CDIM + c] + temb[c];
#pragma unroll
        for (int mi = 0; mi < 4; mi++) {
            int mbase = m0 + wm + mi * 16 + lquad * 4;
#pragma unroll
            for (int r = 0; r < 4; r++) {
                int m = mbase + r;
                if (m < M)
                    out[(out_row_base + m) * CDIM + c] = acc[mi][ni][r] + bias;
            }
        }
    }
}

// ================= fp32 reg-staged GEMM (fallback path only) =================
__device__ __forceinline__ void gemm_f32_body(
    const float* __restrict__ A, const float* __restrict__ W,
    const float* __restrict__ tbias, const float* __restrict__ colw,
    const float* __restrict__ temb, float* __restrict__ out,
    int M, long long out_row_base, int mblk, int nblk,
    bf16* As, bf16* Bs)
{
    constexpr int LDA = 72;
    const int tid = threadIdx.x;
    const int m0 = mblk * 128;
    const int n0 = nblk * 128;
    const int w = tid >> 6, lane = tid & 63;
    const int wm = (w & 1) * 64, wn = (w >> 1) * 64;
    const int lrow = lane & 15, lquad = lane >> 4;

    f32x4 acc[4][4];
#pragma unroll
    for (int a = 0; a < 4; a++)
#pragma unroll
        for (int b = 0; b < 4; b++) acc[a][b] = (f32x4){0.f, 0.f, 0.f, 0.f};

    for (int k0 = 0; k0 < TDIM; k0 += 64) {
        __syncthreads();
#pragma unroll
        for (int i = 0; i < 8; i++) {
            int c = tid + i * 256;
            int row = c >> 4;
            int col4 = (c & 15) << 2;
            int ga = m0 + row; if (ga >= M) ga = M - 1;
            float4 av = *(const float4*)&A[(size_t)ga * TDIM + k0 + col4];
            __attribute__((aligned(8))) bf16 ha[4] =
                {(bf16)av.x, (bf16)av.y, (bf16)av.z, (bf16)av.w};
            *(unsigned long long*)&As[row * LDA + col4] = *(const unsigned long long*)ha;
            float4 bv = *(const float4*)&W[(size_t)(n0 + row) * TDIM + k0 + col4];
            __attribute__((aligned(8))) bf16 hb[4] =
                {(bf16)bv.x, (bf16)bv.y, (bf16)bv.z, (bf16)bv.w};
            *(unsigned long long*)&Bs[row * LDA + col4] = *(const unsigned long long*)hb;
        }
        __syncthreads();
#pragma unroll
        for (int ks = 0; ks < 2; ks++) {
            bf16x8 afr[4], bfr[4];
#pragma unroll
            for (int mi = 0; mi < 4; mi++)
                afr[mi] = *(const bf16x8*)&As[(wm + mi * 16 + lrow) * LDA + ks * 32 + lquad * 8];
#pragma unroll
            for (int ni = 0; ni < 4; ni++)
                bfr[ni] = *(const bf16x8*)&Bs[(wn + ni * 16 + lrow) * LDA + ks * 32 + lquad * 8];
#pragma unroll
            for (int mi = 0; mi < 4; mi++)
#pragma unroll
                for (int ni = 0; ni < 4; ni++)
                    acc[mi][ni] = __builtin_amdgcn_mfma_f32_16x16x32_bf16(
                        afr[mi], bfr[ni], acc[mi][ni], 0, 0, 0);
        }
    }

#pragma unroll
    for (int ni = 0; ni < 4; ni++) {
        int c = n0 + wn + ni * 16 + lrow;
        float bias = tbias[c] + colw[6 * CDIM + c] + temb[c];
#pragma unroll
        for (int mi = 0; mi < 4; mi++) {
            int mbase = m0 + wm + mi * 16 + lquad * 4;
#pragma unroll
            for (int r = 0; r < 4; r++) {
                int m = mbase + r;
                if (m < M)
                    out[(out_row_base + m) * CDIM + c] = acc[mi][ni][r] + bias;
            }
        }
    }
}

// ================= fused mega-kernel (hybrid-GEMM path) =================
__global__ __launch_bounds__(256) void mega(
    const float* __restrict__ users_num, const int* __restrict__ users_cat,
    const float* __restrict__ users_text,
    const float* __restrict__ orders_num, const int* __restrict__ orders_cat,
    const float* __restrict__ orders_text,
    const float* __restrict__ temb,
    const float* __restrict__ unw, const float* __restrict__ unb,
    const float* __restrict__ uctab,
    const float* __restrict__ utb, const float* __restrict__ ucol,
    const float* __restrict__ onw, const float* __restrict__ onb,
    const float* __restrict__ octab,
    const float* __restrict__ otb, const float* __restrict__ ocol,
    const bf16* __restrict__ WbU, const bf16* __restrict__ WbO,
    const int* __restrict__ tbl, float* __restrict__ out)
{
    __shared__ bf16 As[128 * 72];
    __shared__ bf16 Bs[128 * 64];
    int b = blockIdx.x;
    if (b < GEMM_U_BLKS) {
        gemm_hyb_body(users_text, WbU, utb, ucol, temb, out,
                      NU, 120000LL, b >> 1, b & 1, As, Bs);
    } else if (b < MISC_OFF) {
        int bb = b - GEMM_U_BLKS;
        gemm_hyb_body(orders_text, WbO, otb, ocol, temb + CDIM, out,
                      NO, 200000LL, bb >> 1, bb & 1, As, Bs);
    } else if (b < IDX_OFF) {
        misc_body(b - MISC_OFF, users_num, users_cat, orders_num, orders_cat,
                  temb, unw, unb, uctab, ucol, onw, onb, octab, ocol, out);
    } else {
        idx_body(b - IDX_OFF, tbl, out);
    }
}

// ================= fallback mega (fp32 reg-staged GEMM, no prep W) =================
__global__ __launch_bounds__(256) void mega_fb(
    const float* __restrict__ users_num, const int* __restrict__ users_cat,
    const float* __restrict__ users_text,
    const float* __restrict__ orders_num, const int* __restrict__ orders_cat,
    const float* __restrict__ orders_text,
    const float* __restrict__ temb,
    const float* __restrict__ unw, const float* __restrict__ unb,
    const float* __restrict__ uctab, const float* __restrict__ utw,
    const float* __restrict__ utb, const float* __restrict__ ucol,
    const float* __restrict__ onw, const float* __restrict__ onb,
    const float* __restrict__ octab, const float* __restrict__ otw,
    const float* __restrict__ otb, const float* __restrict__ ocol,
    const int* __restrict__ tbl, float* __restrict__ out)
{
    __shared__ bf16 As[128 * 72];
    __shared__ bf16 Bs[128 * 72];
    int b = blockIdx.x;
    if (b < GEMM_U_BLKS) {
        gemm_f32_body(users_text, utw, utb, ucol, temb, out,
                      NU, 120000LL, b >> 1, b & 1, As, Bs);
    } else if (b < MISC_OFF) {
        int bb = b - GEMM_U_BLKS;
        gemm_f32_body(orders_text, otw, otb, ocol, temb + CDIM, out,
                      NO, 200000LL, bb >> 1, bb & 1, As, Bs);
    } else if (b < IDX_OFF) {
        misc_body(b - MISC_OFF, users_num, users_cat, orders_num, orders_cat,
                  temb, unw, unb, uctab, ucol, onw, onb, octab, ocol, out);
    } else {
        idx_body(b - IDX_OFF, tbl, out);
    }
}

__global__ void edges_fill(const int* __restrict__ edge, int* __restrict__ counts,
                           unsigned long long* __restrict__ pairs)
{
    edges_body(blockIdx.x, edge, counts, pairs);
}

extern "C" void kernel_launch(void* const* d_in, const int* in_sizes, int n_in,
                              void* d_out, int out_size, void* d_ws, size_t ws_size,
                              hipStream_t stream)
{
    const float* users_num   = (const float*)d_in[0];
    const int*   users_cat   = (const int*)d_in[1];
    const float* users_text  = (const float*)d_in[2];
    const float* orders_num  = (const float*)d_in[3];
    const int*   orders_cat  = (const int*)d_in[4];
    const float* orders_text = (const float*)d_in[5];
    const int*   edge_index  = (const int*)d_in[6];
    const float* table_emb   = (const float*)d_in[7];
    const float* u_num_w   = (const float*)d_in[8];
    const float* u_num_b   = (const float*)d_in[9];
    const float* u_cat_tab = (const float*)d_in[10];
    const float* u_txt_w   = (const float*)d_in[11];
    const float* u_txt_b   = (const float*)d_in[12];
    const float* u_col     = (const float*)d_in[13];
    const float* o_num_w   = (const float*)d_in[14];
    const float* o_num_b   = (const float*)d_in[15];
    const float* o_cat_tab = (const float*)d_in[16];
    const float* o_txt_w   = (const float*)d_in[17];
    const float* o_txt_b   = (const float*)d_in[18];
    const float* o_col     = (const float*)d_in[19];
    float* out = (float*)d_out;

    int* counts = (int*)d_ws;
    unsigned long long* pairs = (unsigned long long*)((char*)d_ws + WS_PAIRS_OFF);
    int* tbl = (int*)((char*)d_ws + WS_TBL_OFF);

    hipMemsetAsync(counts, 0, NO * sizeof(int), stream);

    if (ws_size >= WS_NEED) {
        bf16* WbU = (bf16*)((char*)d_ws + WS_WB_U_OFF);
        bf16* WbO = (bf16*)((char*)d_ws + WS_WB_O_OFF);
        prep<<<PREP_BLKS, 256, 0, stream>>>(edge_index, counts, pairs,
                                            u_txt_w, o_txt_w, WbU, WbO);
        build_tbl<<<(NO + 255) / 256, 256, 0, stream>>>(counts, pairs, tbl);
        mega<<<TOTAL_BLKS, 256, 0, stream>>>(
            users_num, users_cat, users_text, orders_num, orders_cat, orders_text,
            table_emb, u_num_w, u_num_b, u_cat_tab, u_txt_b, u_col,
            o_num_w, o_num_b, o_cat_tab, o_txt_b, o_col,
            WbU, WbO, tbl, out);
    } else {
        edges_fill<<<P_EDGE, 256, 0, stream>>>(edge_index, counts, pairs);
        build_tbl<<<(NO + 255) / 256, 256, 0, stream>>>(counts, pairs, tbl);
        mega_fb<<<TOTAL_BLKS, 256, 0, stream>>>(
            users_num, users_cat, users_text, orders_num, orders_cat, orders_text,
            table_emb, u_num_w, u_num_b, u_cat_tab, u_txt_w, u_txt_b, u_col,
            o_num_w, o_num_b, o_cat_tab, o_txt_w, o_txt_b, o_col, tbl, out);
    }
}